// Round 2
// baseline (1065.412 us; speedup 1.0000x reference)
//
#include <hip/hip_runtime.h>

#define R_ 16
#define T_ 512
#define N_ 256
#define D_ 22
#define DTOT 1278  // 2*(T-1) + (N-1) + 1 diagonals; divisible by 3

constexpr float TWO_LOG2E = 2.8853900817779268f;  // 2*log2(e)
constexpr float LOG2E     = 1.4426950408889634f;

// ---------------------------------------------------------------------------
// Kernel 1: pre[r,t,i,j] = (b1[j] + sum_k x[r,t,i,k]*W1[k,j]) * 2log2e
// Fully parallel, memory-bound. LDS-staged so it is safe in-place (pre==runs).
// ---------------------------------------------------------------------------
__global__ __launch_bounds__(256) void pre_kernel(const float* __restrict__ runs,
                                                  const float* __restrict__ W1,
                                                  const float* __restrict__ b1,
                                                  float* __restrict__ pre) {
    __shared__ float sx[256 * 23];  // +1 pad -> stride 23 (coprime with 32 banks)
    const size_t base = (size_t)blockIdx.x * (256 * 22);

    for (int m = threadIdx.x; m < 256 * 22; m += 256) {
        int row = m / 22;
        int k = m - row * 22;
        sx[row * 23 + k] = runs[base + m];
    }
    __syncthreads();

    float x[22];
#pragma unroll
    for (int k = 0; k < 22; ++k) x[k] = sx[threadIdx.x * 23 + k];

    float acc[22];
#pragma unroll
    for (int j = 0; j < 22; ++j) acc[j] = b1[j];   // uniform -> s_load
#pragma unroll
    for (int k = 0; k < 22; ++k) {
#pragma unroll
        for (int j = 0; j < 22; ++j)
            acc[j] = fmaf(x[k], W1[k * 22 + j], acc[j]);  // uniform W1 -> s_load
    }
#pragma unroll
    for (int j = 0; j < 22; ++j) sx[threadIdx.x * 23 + j] = acc[j] * TWO_LOG2E;
    __syncthreads();

    for (int m = threadIdx.x; m < 256 * 22; m += 256) {
        int row = m / 22;
        int k = m - row * 22;
        pre[base + m] = sx[row * 23 + k];
    }
}

// ---------------------------------------------------------------------------
// Kernel 2: diagonal-wavefront recurrence. One block per run.
// Step (t,i) lives on diagonal d=2t+i; both deps (t,i-1) and (t-1,i+1) are on
// d-1, and within a diagonal all i share parity so writes (i+1) never collide
// with reads (i, i+2)  ->  one barrier per diagonal.
// 128 steps/diagonal x 4 lanes/step = 512 threads. comm[258] lives in LDS.
// Lane l of a step handles hidden units j = 6*l .. 6*l+5 (j<22; tail zeroed).
// Barriers are raw s_barrier + lgkmcnt(0) only (NO vmcnt drain) so the
// global prefetch loads for diagonal d+2 stay in flight across barriers.
// ---------------------------------------------------------------------------
__global__ __launch_bounds__(512, 1) void wave_kernel(const float* __restrict__ pre,
                                                      const float* __restrict__ comm0,
                                                      const float* __restrict__ W1,
                                                      const float* __restrict__ W2,
                                                      const float* __restrict__ b2,
                                                      float* __restrict__ out) {
    __shared__ float comm[N_ + 2];
    const int tid = threadIdx.x;
    const int r = blockIdx.x;
    const int sidx = tid >> 2;   // step index within diagonal (0..127)
    const int l = tid & 3;       // lane within step
    const int jb = l * 6;

    if (tid < N_ + 2)
        comm[tid] = (tid == 0 || tid == N_ + 1) ? 0.f : comm0[r * (N_ + 2) + tid];

    // per-lane weight slices (zero-padded past j=21)
    float A2[6], B2[6], Wa[6], Wb[6];
#pragma unroll
    for (int q = 0; q < 6; ++q) {
        int j = jb + q;
        bool jv = (j < 22);
        A2[q] = jv ? W1[484 + j] * TWO_LOG2E : 0.f;  // W1[22][j] (left)
        B2[q] = jv ? W1[506 + j] * TWO_LOG2E : 0.f;  // W1[23][j] (right)
        Wa[q] = jv ? W2[2 * j] : 0.f;
        Wb[q] = jv ? W2[2 * j + 1] : 0.f;
    }
    const float bb0 = b2[0], bb1 = b2[1];
    const float* preR = pre + (size_t)r * ((size_t)T_ * N_ * 22);
    float* outR = out + (size_t)r * ((size_t)T_ * N_);
    __syncthreads();  // full sync once (covers comm init)

    // float2 index of the 3rd pair, clamped so lane 3 never reads past the row
    // (lane 3 re-reads pre[20..21]; they feed only the zeroed j=22,23 weights)
    const int q2i = (jb + 4 <= 20) ? ((jb >> 1) + 2) : 10;

    float pA[6], pB[6], pC[6];

    auto PF = [&](float* buf, int d) {
        int tl = (d > 255) ? ((d - 254) >> 1) : 0;
        int t = tl + sidx;
        int i = d - 2 * t;
        bool v = (t < T_) && (i >= 0) && (d < DTOT);
        size_t row = v ? ((size_t)t * N_ + i) : 0;  // clamp invalid -> row 0 (value unused)
        const float2* p = reinterpret_cast<const float2*>(preR + row * 22);
        float2 a = p[jb >> 1];
        float2 b = p[(jb >> 1) + 1];
        float2 c = p[q2i];
        buf[0] = a.x; buf[1] = a.y; buf[2] = b.x;
        buf[3] = b.y; buf[4] = c.x; buf[5] = c.y;
    };

    auto ST = [&](int d, float* buf) {
        int tl = (d > 255) ? ((d - 254) >> 1) : 0;
        int t = tl + sidx;
        int i = d - 2 * t;
        bool v = (t < T_) && (i >= 0);
        float left = 0.f, right = 0.f;
        if (v) { left = comm[i]; right = comm[i + 2]; }
        float a0 = 0.f, a1 = 0.f;
#pragma unroll
        for (int q = 0; q < 6; ++q) {
            // u = 2*log2e * (pre + left*W1[22][j] + right*W1[23][j])
            float u = fmaf(right, B2[q], fmaf(left, A2[q], buf[q]));
            float e = __builtin_amdgcn_exp2f(u);                        // e^(2z) as 2^u
            float h = fmaf(-2.f, __builtin_amdgcn_rcpf(1.f + e), 1.f);  // tanh(z)
            a0 = fmaf(h, Wa[q], a0);
            a1 = fmaf(h, Wb[q], a1);
        }
        // 4-lane butterfly: all lanes of the step get full sums
        a0 += __shfl_xor(a0, 1); a1 += __shfl_xor(a1, 1);
        a0 += __shfl_xor(a0, 2); a1 += __shfl_xor(a1, 2);
        if (v && l == 0) {
            outR[(size_t)t * N_ + i] = a0 + bb0;                       // control (raw)
            float o1 = a1 + bb1;
            comm[i + 1] = __builtin_amdgcn_rcpf(
                1.f + __builtin_amdgcn_exp2f(-LOG2E * o1));            // sigmoid
        }
    };

    // lgkmcnt(0) ensures this wave's LDS ops are complete before the barrier;
    // the trailing empty asm is a compiler fence so no comm[] access is
    // hoisted above s_barrier (raw s_barrier is NOT an LLVM memory fence).
#define BAR() do { asm volatile("s_waitcnt lgkmcnt(0)" ::: "memory"); \
                   __builtin_amdgcn_s_barrier();                      \
                   asm volatile("" ::: "memory"); } while (0)

    PF(pA, 0);
    PF(pB, 1);
    for (int d = 0; d < DTOT; d += 3) {
        PF(pC, d + 2); ST(d,     pA); BAR();
        PF(pA, d + 3); ST(d + 1, pB); BAR();
        PF(pB, d + 4); ST(d + 2, pC); BAR();
    }
#undef BAR
}

// ---------------------------------------------------------------------------
extern "C" void kernel_launch(void* const* d_in, const int* in_sizes, int n_in,
                              void* d_out, int out_size, void* d_ws, size_t ws_size,
                              hipStream_t stream) {
    const float* runs  = (const float*)d_in[0];
    const float* comm0 = (const float*)d_in[1];
    const float* W1    = (const float*)d_in[2];
    const float* b1    = (const float*)d_in[3];
    const float* W2    = (const float*)d_in[4];
    const float* b2    = (const float*)d_in[5];
    float* out = (float*)d_out;

    const size_t preBytes = (size_t)R_ * T_ * N_ * 22 * sizeof(float);
    // Prefer workspace; fall back to in-place overwrite of runs (harness
    // restores d_in from pristine copies before every launch, and pre_kernel
    // stages through LDS so in-place is race-free).
    float* pre = (ws_size >= preBytes) ? (float*)d_ws : (float*)d_in[0];

    pre_kernel<<<(R_ * T_ * N_) / 256, 256, 0, stream>>>(runs, W1, b1, pre);
    wave_kernel<<<R_, 512, 0, stream>>>(pre, comm0, W1, W2, b2, out);
}